// Round 2
// baseline (1238.357 us; speedup 1.0000x reference)
//
#include <hip/hip_runtime.h>
#include <hip/hip_bf16.h>
#include <cstdint>

#define DEVINL __device__ __forceinline__

using bf16 = __hip_bfloat16;
typedef __bf16 bf16x8 __attribute__((ext_vector_type(8)));
typedef float f32x4 __attribute__((ext_vector_type(4)));

static constexpr int MTOK = 131072;  // B*N tokens

DEVINL unsigned short bfbits(float v) {
  bf16 h = __float2bfloat16(v);
  return *reinterpret_cast<unsigned short*>(&h);
}

// ---------------- weights fp32 -> bf16 (concatenated: in_w, out_w, w1, w2) --
__global__ __launch_bounds__(256) void cvt_w(
    const float* __restrict__ w0, const float* __restrict__ w1,
    const float* __restrict__ w2, const float* __restrict__ w3,
    bf16* __restrict__ out) {
  int i = blockIdx.x * 256 + threadIdx.x;
  float v;
  if (i < 196608)      v = w0[i];
  else if (i < 262144) v = w1[i - 196608];
  else if (i < 524288) v = w2[i - 262144];
  else                 v = w3[i - 524288];
  out[i] = __float2bfloat16(v);
}

// ---------------- LayerNorm (+optional window partition), fp32 -> bf16 ------
// one wave per token (C=256 -> 4 elems/lane, float4 vectorized)
template <bool REMAP>
__global__ __launch_bounds__(256) void ln_kern(
    const float* __restrict__ x, const float* __restrict__ gw,
    const float* __restrict__ bw, bf16* __restrict__ out) {
  const int lane = threadIdx.x & 63;
  const int wv = threadIdx.x >> 6;
  const long tok = (long)blockIdx.x * 4 + wv;
  const float4 v = *(const float4*)(x + tok * 256 + lane * 4);
  float s = v.x + v.y + v.z + v.w;
#pragma unroll
  for (int off = 32; off > 0; off >>= 1) s += __shfl_xor(s, off);
  const float mean = s * (1.0f / 256.0f);
  const float dx = v.x - mean, dy = v.y - mean, dz = v.z - mean, dw = v.w - mean;
  float q = dx * dx + dy * dy + dz * dz + dw * dw;
#pragma unroll
  for (int off = 32; off > 0; off >>= 1) q += __shfl_xor(q, off);
  const float inv = rsqrtf(q * (1.0f / 256.0f) + 1e-5f);
  long drow;
  if (REMAP) {
    const int b = (int)(tok >> 14);
    const int n = (int)(tok & 16383);
    const int row = n >> 7, col = n & 127;
    const int w = b * 256 + (row >> 3) * 16 + (col >> 3);
    const int t = (row & 7) * 8 + (col & 7);
    drow = ((long)w * 64 + t) * 256;
  } else {
    drow = tok * 256;
  }
  const float4 g = *(const float4*)(gw + lane * 4);
  const float4 bb = *(const float4*)(bw + lane * 4);
  ushort4 o;
  o.x = bfbits(dx * inv * g.x + bb.x);
  o.y = bfbits(dy * inv * g.y + bb.y);
  o.z = bfbits(dz * inv * g.z + bb.z);
  o.w = bfbits(dw * inv * g.w + bb.w);
  *(ushort4*)((unsigned short*)out + drow + lane * 4) = o;
}

// ---------------- streaming register GEMM: C[M,N] = A[M,K] @ B[N,K]^T -------
// No LDS, no barriers. Per-wave direct global->VGPR fragment loads, register
// ping-pong with 1-chunk lookahead -> compiler emits fine-grained vmcnt(N).
// Grid: 1-D, XCD-aware decode: xcd = lid&7, n-tile fastest within XCD stripe.
enum { EPI_QKV = 0, EPI_OUTPROJ = 1, EPI_GELU = 2, EPI_RESID = 3 };

DEVINL void ldc(bf16x8 (&aa)[4], bf16x8 (&bb)[4],
                const bf16* const (&Ap)[4], const bf16* const (&Bp)[4],
                int koff) {
#pragma unroll
  for (int t = 0; t < 4; ++t) {
    aa[t] = *(const bf16x8*)(Ap[t] + koff);
    bb[t] = *(const bf16x8*)(Bp[t] + koff);
  }
}

DEVINL void mf16(f32x4 (&acc)[4][4], const bf16x8 (&aa)[4], const bf16x8 (&bb)[4]) {
#pragma unroll
  for (int mt = 0; mt < 4; ++mt) {
#pragma unroll
    for (int nt = 0; nt < 4; ++nt) {
      acc[mt][nt] = __builtin_amdgcn_mfma_f32_16x16x32_bf16(
          aa[mt], bb[nt], acc[mt][nt], 0, 0, 0);
    }
  }
}

template <int K, int NT, int EPI>
__global__ __launch_bounds__(256, 3) void gemm_stream(
    const bf16* __restrict__ A, const bf16* __restrict__ Bw,
    const float* __restrict__ bias,
    bf16* __restrict__ oQ, bf16* __restrict__ oK, bf16* __restrict__ oV,
    const float* __restrict__ resid, float* __restrict__ of32,
    bf16* __restrict__ obf, int ldo) {
  const int tid = threadIdx.x;
  const int lane = tid & 63, wv = tid >> 6;
  const int quad = lane >> 4, l16 = lane & 15;
  const int wm = wv >> 1, wn = wv & 1;
  // XCD-aware block decode: both/all NT n-tiles of an m-tile land on one XCD
  const int lid = blockIdx.x;
  const int xcd = lid & 7;
  const int s = lid >> 3;
  const int ntile = s % NT;
  const int mtile = (s / NT) * 8 + xcd;
  const long m0 = (long)mtile * 128;
  const int n0 = ntile * 128;

  const bf16* Ap[4];
  const bf16* Bp[4];
#pragma unroll
  for (int t = 0; t < 4; ++t) {
    Ap[t] = A + (long)(m0 + wm * 64 + t * 16 + l16) * K + quad * 8;
    Bp[t] = Bw + (long)(n0 + wn * 64 + t * 16 + l16) * K + quad * 8;
  }

  const f32x4 fz = {0.f, 0.f, 0.f, 0.f};
  f32x4 acc[4][4];
#pragma unroll
  for (int a = 0; a < 4; ++a) {
#pragma unroll
    for (int b = 0; b < 4; ++b) acc[a][b] = fz;
  }

  constexpr int NC = K / 32;  // 32-wide K chunks; NC is even for all our K
  bf16x8 a0[4], b0[4], a1[4], b1[4];
  ldc(a0, b0, Ap, Bp, 0);
#pragma unroll 1
  for (int c = 0; c < NC - 2; c += 2) {
    ldc(a1, b1, Ap, Bp, (c + 1) * 32);
    mf16(acc, a0, b0);
    ldc(a0, b0, Ap, Bp, (c + 2) * 32);
    mf16(acc, a1, b1);
  }
  ldc(a1, b1, Ap, Bp, (NC - 1) * 32);
  mf16(acc, a0, b0);
  mf16(acc, a1, b1);

  // epilogue: C/D layout col=lane&15, row=quad*4+reg  [m89-verified]
#pragma unroll
  for (int mt = 0; mt < 4; ++mt) {
#pragma unroll
    for (int nt = 0; nt < 4; ++nt) {
      const long mb = m0 + wm * 64 + mt * 16 + quad * 4;
      const int j = n0 + wn * 64 + nt * 16 + l16;
      const float bj = bias[j];
#pragma unroll
      for (int r = 0; r < 4; ++r) {
        const long m = mb + r;
        const float v = acc[mt][nt][r] + bj;
        if constexpr (EPI == EPI_QKV) {
          const int w = (int)(m >> 6), t = (int)(m & 63);
          const int region = j >> 8, hh = (j >> 5) & 7, d = j & 31;
          const long hb = (long)w * 8 + hh;
          if (region == 0)      oQ[(hb * 64 + t) * 32 + d] = __float2bfloat16(v);
          else if (region == 1) oK[(hb * 64 + t) * 32 + d] = __float2bfloat16(v);
          else                  oV[(hb * 32 + d) * 64 + t] = __float2bfloat16(v);  // V^T
        } else if constexpr (EPI == EPI_OUTPROJ) {
          const int w = (int)(m >> 6), t = (int)(m & 63);
          const int b = w >> 8, wi = w & 255;
          const int row = (wi >> 4) * 8 + (t >> 3);
          const int col = (wi & 15) * 8 + (t & 7);
          const long addr = ((long)b * 16384 + row * 128 + col) * 256 + j;
          of32[addr] = v + resid[addr];
        } else if constexpr (EPI == EPI_GELU) {
          const float g = 0.5f * v * (1.0f + erff(v * 0.70710678118654752f));
          obf[m * (long)ldo + j] = __float2bfloat16(g);
        } else {  // EPI_RESID: accumulate into d_out
          const long addr = m * 256 + j;
          of32[addr] += v;
        }
      }
    }
  }
}

// ---------------- fused window attention ------------------------------------
// 1 block / window (64 tokens); wave wv handles heads 2wv, 2wv+1.
__global__ __launch_bounds__(256) void attn_kern(
    const bf16* __restrict__ Qb, const bf16* __restrict__ Kb,
    const bf16* __restrict__ Vtb, bf16* __restrict__ O) {
  __shared__ __align__(16) unsigned short P[4][64 * 72];
  const int lane = threadIdx.x & 63;
  const int wv = threadIdx.x >> 6;
  const int quad = lane >> 4, l16 = lane & 15;
  const long w = blockIdx.x;
  unsigned short* Pw = &P[wv][0];
  const float SC = 0.17677669529663689f;  // 1/sqrt(32)
  const f32x4 fz = {0.f, 0.f, 0.f, 0.f};

#pragma unroll 1
  for (int hi = 0; hi < 2; ++hi) {
    const int h = wv * 2 + hi;
    const bf16* qp = Qb + ((w * 8 + h) * 64) * 32;
    const bf16* kp = Kb + ((w * 8 + h) * 64) * 32;
    const bf16* vt = Vtb + ((w * 8 + h) * 32) * 64;

    bf16x8 qf[4], kf[4];
#pragma unroll
    for (int mt = 0; mt < 4; ++mt)
      qf[mt] = *(const bf16x8*)(qp + (mt * 16 + l16) * 32 + quad * 8);
#pragma unroll
    for (int nt = 0; nt < 4; ++nt)
      kf[nt] = *(const bf16x8*)(kp + (nt * 16 + l16) * 32 + quad * 8);

    f32x4 s[4][4];
#pragma unroll
    for (int a = 0; a < 4; ++a) {
#pragma unroll
      for (int b = 0; b < 4; ++b) s[a][b] = fz;
    }
#pragma unroll
    for (int mt = 0; mt < 4; ++mt) {
#pragma unroll
      for (int nt = 0; nt < 4; ++nt) {
        s[mt][nt] = __builtin_amdgcn_mfma_f32_16x16x32_bf16(qf[mt], kf[nt],
                                                            s[mt][nt], 0, 0, 0);
      }
    }

#pragma unroll
    for (int mt = 0; mt < 4; ++mt) {
#pragma unroll
      for (int r = 0; r < 4; ++r) {
        float a0 = s[mt][0][r] * SC, a1 = s[mt][1][r] * SC;
        float a2 = s[mt][2][r] * SC, a3 = s[mt][3][r] * SC;
        float mx = fmaxf(fmaxf(a0, a1), fmaxf(a2, a3));
#pragma unroll
        for (int off = 8; off > 0; off >>= 1) mx = fmaxf(mx, __shfl_xor(mx, off));
        a0 = __expf(a0 - mx); a1 = __expf(a1 - mx);
        a2 = __expf(a2 - mx); a3 = __expf(a3 - mx);
        float sm = a0 + a1 + a2 + a3;
#pragma unroll
        for (int off = 8; off > 0; off >>= 1) sm += __shfl_xor(sm, off);
        const float iv = 1.0f / sm;
        const int rp = (mt * 16 + quad * 4 + r) * 72;
        Pw[rp + l16]      = bfbits(a0 * iv);
        Pw[rp + 16 + l16] = bfbits(a1 * iv);
        Pw[rp + 32 + l16] = bfbits(a2 * iv);
        Pw[rp + 48 + l16] = bfbits(a3 * iv);
      }
    }

    bf16x8 vf[2][2];
#pragma unroll
    for (int kt = 0; kt < 2; ++kt) {
#pragma unroll
      for (int dt = 0; dt < 2; ++dt)
        vf[kt][dt] = *(const bf16x8*)(vt + (dt * 16 + l16) * 64 + kt * 32 + quad * 8);
    }
    f32x4 oa[4][2];
#pragma unroll
    for (int a = 0; a < 4; ++a) { oa[a][0] = fz; oa[a][1] = fz; }
#pragma unroll
    for (int mt = 0; mt < 4; ++mt) {
      const unsigned short* pr = Pw + (mt * 16 + l16) * 72 + quad * 8;
      const bf16x8 p0 = *(const bf16x8*)(pr);
      const bf16x8 p1 = *(const bf16x8*)(pr + 32);
#pragma unroll
      for (int dt = 0; dt < 2; ++dt) {
        oa[mt][dt] = __builtin_amdgcn_mfma_f32_16x16x32_bf16(p0, vf[0][dt], oa[mt][dt], 0, 0, 0);
        oa[mt][dt] = __builtin_amdgcn_mfma_f32_16x16x32_bf16(p1, vf[1][dt], oa[mt][dt], 0, 0, 0);
      }
    }

#pragma unroll
    for (int mt = 0; mt < 4; ++mt) {
#pragma unroll
      for (int dt = 0; dt < 2; ++dt) {
#pragma unroll
        for (int r = 0; r < 4; ++r) {
          O[(w * 64 + mt * 16 + quad * 4 + r) * 256 + h * 32 + dt * 16 + l16] =
              __float2bfloat16(oa[mt][dt][r]);
        }
      }
    }
  }
}

// ---------------- launch -----------------------------------------------------
extern "C" void kernel_launch(void* const* d_in, const int* in_sizes, int n_in,
                              void* d_out, int out_size, void* d_ws, size_t ws_size,
                              hipStream_t stream) {
  const float* x     = (const float*)d_in[0];
  const float* ln1g  = (const float*)d_in[1];
  const float* ln1b  = (const float*)d_in[2];
  const float* in_w  = (const float*)d_in[3];
  const float* in_b  = (const float*)d_in[4];
  const float* out_w = (const float*)d_in[5];
  const float* out_b = (const float*)d_in[6];
  const float* ln2g  = (const float*)d_in[7];
  const float* ln2b  = (const float*)d_in[8];
  const float* w1    = (const float*)d_in[9];
  const float* b1    = (const float*)d_in[10];
  const float* w2    = (const float*)d_in[11];
  const float* b2    = (const float*)d_in[12];
  float* out = (float*)d_out;

  char* ws = (char*)d_ws;
  const size_t MB = 1ull << 20;
  bf16* Wc   = (bf16*)ws;
  bf16* Wqkv = Wc;
  bf16* Wo   = Wc + 196608;
  bf16* W1c  = Wc + 262144;
  bf16* W2c  = Wc + 524288;
  bf16* XW   = (bf16*)(ws + 2 * MB);
  bf16* Qb   = (bf16*)(ws + 66 * MB);
  bf16* Kb   = (bf16*)(ws + 130 * MB);
  bf16* Vtb  = (bf16*)(ws + 194 * MB);
  bf16* H1   = (bf16*)(ws + 66 * MB);
  bf16* Obuf = XW;
  bf16* Hbuf = XW;

  cvt_w<<<3072, 256, 0, stream>>>(in_w, out_w, w1, w2, Wc);
  ln_kern<true><<<MTOK / 4, 256, 0, stream>>>(x, ln1g, ln1b, XW);
  gemm_stream<256, 6, EPI_QKV><<<1024 * 6, 256, 0, stream>>>(
      XW, Wqkv, in_b, Qb, Kb, Vtb, nullptr, nullptr, nullptr, 0);
  attn_kern<<<2048, 256, 0, stream>>>(Qb, Kb, Vtb, Obuf);
  gemm_stream<256, 2, EPI_OUTPROJ><<<1024 * 2, 256, 0, stream>>>(
      Obuf, Wo, out_b, nullptr, nullptr, nullptr, x, out, nullptr, 0);
  ln_kern<false><<<MTOK / 4, 256, 0, stream>>>(out, ln2g, ln2b, Hbuf);
  gemm_stream<256, 8, EPI_GELU><<<1024 * 8, 256, 0, stream>>>(
      Hbuf, W1c, b1, nullptr, nullptr, nullptr, nullptr, nullptr, H1, 1024);
  gemm_stream<1024, 2, EPI_RESID><<<1024 * 2, 256, 0, stream>>>(
      H1, W2c, b2, nullptr, nullptr, nullptr, nullptr, out, nullptr, 0);
}

// Round 3
// 941.946 us; speedup vs baseline: 1.3147x; 1.3147x over previous
//
#include <hip/hip_runtime.h>
#include <hip/hip_bf16.h>
#include <cstdint>

#define DEVINL __device__ __forceinline__

using bf16 = __hip_bfloat16;
typedef __bf16 bf16x8 __attribute__((ext_vector_type(8)));
typedef float f32x4 __attribute__((ext_vector_type(4)));

static constexpr int MTOK = 131072;  // B*N tokens

DEVINL void async_ld16(const void* g, void* l) {
  __builtin_amdgcn_global_load_lds(
      (__attribute__((address_space(1))) void*)(g),
      (__attribute__((address_space(3))) void*)(l), 16, 0, 0);
}

DEVINL unsigned short bfbits(float v) {
  bf16 h = __float2bfloat16(v);
  return *reinterpret_cast<unsigned short*>(&h);
}

// ---------------- weights fp32 -> bf16 (concatenated: in_w, out_w, w1, w2) --
__global__ __launch_bounds__(256) void cvt_w(
    const float* __restrict__ w0, const float* __restrict__ w1,
    const float* __restrict__ w2, const float* __restrict__ w3,
    bf16* __restrict__ out) {
  int i = blockIdx.x * 256 + threadIdx.x;
  float v;
  if (i < 196608)      v = w0[i];
  else if (i < 262144) v = w1[i - 196608];
  else if (i < 524288) v = w2[i - 262144];
  else                 v = w3[i - 524288];
  out[i] = __float2bfloat16(v);
}

// ---------------- LayerNorm (+optional window partition), fp32 -> bf16 ------
// one wave per token (C=256 -> 4 elems/lane, float4 vectorized)
template <bool REMAP>
__global__ __launch_bounds__(256) void ln_kern(
    const float* __restrict__ x, const float* __restrict__ gw,
    const float* __restrict__ bw, bf16* __restrict__ out) {
  const int lane = threadIdx.x & 63;
  const int wv = threadIdx.x >> 6;
  const long tok = (long)blockIdx.x * 4 + wv;
  const float4 v = *(const float4*)(x + tok * 256 + lane * 4);
  float s = v.x + v.y + v.z + v.w;
#pragma unroll
  for (int off = 32; off > 0; off >>= 1) s += __shfl_xor(s, off);
  const float mean = s * (1.0f / 256.0f);
  const float dx = v.x - mean, dy = v.y - mean, dz = v.z - mean, dw = v.w - mean;
  float q = dx * dx + dy * dy + dz * dz + dw * dw;
#pragma unroll
  for (int off = 32; off > 0; off >>= 1) q += __shfl_xor(q, off);
  const float inv = rsqrtf(q * (1.0f / 256.0f) + 1e-5f);
  long drow;
  if (REMAP) {
    const int b = (int)(tok >> 14);
    const int n = (int)(tok & 16383);
    const int row = n >> 7, col = n & 127;
    const int w = b * 256 + (row >> 3) * 16 + (col >> 3);
    const int t = (row & 7) * 8 + (col & 7);
    drow = ((long)w * 64 + t) * 256;
  } else {
    drow = tok * 256;
  }
  const float4 g = *(const float4*)(gw + lane * 4);
  const float4 bb = *(const float4*)(bw + lane * 4);
  ushort4 o;
  o.x = bfbits(dx * inv * g.x + bb.x);
  o.y = bfbits(dy * inv * g.y + bb.y);
  o.z = bfbits(dz * inv * g.z + bb.z);
  o.w = bfbits(dw * inv * g.w + bb.w);
  *(ushort4*)((unsigned short*)out + drow + lane * 4) = o;
}

// ---------------- GEMM: C[M,N] = A[M,K] @ B[N,K]^T (+epilogue) --------------
// R1 structure + double-buffered LDS with raw single-barrier async pipeline:
// prefetch for tile i+1 issued AFTER the barrier -> stays in flight across the
// compute of tile i (no compiler-forced vmcnt(0)+syncthreads drain).
enum { EPI_QKV = 0, EPI_OUTPROJ = 1, EPI_GELU = 2, EPI_RESID = 3 };

template <int K, int EPI>
__global__ __launch_bounds__(256) void gemm_db(
    const bf16* __restrict__ A, const bf16* __restrict__ Bw,
    const float* __restrict__ bias,
    bf16* __restrict__ oQ, bf16* __restrict__ oK, bf16* __restrict__ oV,
    const float* __restrict__ resid, float* __restrict__ of32,
    bf16* __restrict__ obf, int ldo) {
  __shared__ __align__(16) unsigned short As[2][128 * 64];
  __shared__ __align__(16) unsigned short Bs[2][128 * 64];
  const int tid = threadIdx.x;
  const int lane = tid & 63, wv = tid >> 6;
  const int quad = lane >> 4, l16 = lane & 15;
  const int wm = wv >> 1, wn = wv & 1;
  const long m0 = (long)blockIdx.x * 128;
  const int n0 = blockIdx.y * 128;

  auto stage = [&](int i, int buf) {
    const int k0 = i * 64;
#pragma unroll
    for (int p = 0; p < 4; ++p) {
      const int f = p * 256 + tid;
      const int row = f >> 3;
      const int c8 = (f & 7) ^ (row & 7);
      async_ld16(A + (m0 + row) * K + (k0 + c8 * 8), (char*)&As[buf][0] + f * 16);
      async_ld16(Bw + (long)(n0 + row) * K + (k0 + c8 * 8), (char*)&Bs[buf][0] + f * 16);
    }
  };

  const f32x4 fz = {0.f, 0.f, 0.f, 0.f};
  f32x4 acc[4][4];
#pragma unroll
  for (int a = 0; a < 4; ++a) {
#pragma unroll
    for (int b = 0; b < 4; ++b) acc[a][b] = fz;
  }

  constexpr int NI = K / 64;
  stage(0, 0);
#pragma unroll 1
  for (int i = 0; i < NI; ++i) {
    // wait own staging loads for buf[i&1] (prefetch for i+1 not yet issued),
    // then raw barrier: all waves' DMA done & all done reading buf[(i-1)&1].
    __builtin_amdgcn_s_waitcnt(0x0F70);  // vmcnt(0), lgkm/exp unconstrained
    __builtin_amdgcn_sched_barrier(0);
    __builtin_amdgcn_s_barrier();
    __builtin_amdgcn_sched_barrier(0);
    if (i + 1 < NI) stage(i + 1, (i + 1) & 1);
    const unsigned short* Asb = &As[i & 1][0];
    const unsigned short* Bsb = &Bs[i & 1][0];
#pragma unroll
    for (int kk = 0; kk < 2; ++kk) {
      bf16x8 af[4], bfr[4];
#pragma unroll
      for (int mt = 0; mt < 4; ++mt) {
        const int row = wm * 64 + mt * 16 + l16;
        const int c8 = (kk * 4 + quad) ^ (row & 7);
        af[mt] = *(const bf16x8*)(Asb + row * 64 + c8 * 8);
      }
#pragma unroll
      for (int nt = 0; nt < 4; ++nt) {
        const int row = wn * 64 + nt * 16 + l16;
        const int c8 = (kk * 4 + quad) ^ (row & 7);
        bfr[nt] = *(const bf16x8*)(Bsb + row * 64 + c8 * 8);
      }
#pragma unroll
      for (int mt = 0; mt < 4; ++mt) {
#pragma unroll
        for (int nt = 0; nt < 4; ++nt) {
          acc[mt][nt] = __builtin_amdgcn_mfma_f32_16x16x32_bf16(
              af[mt], bfr[nt], acc[mt][nt], 0, 0, 0);
        }
      }
    }
  }

  // epilogue: C/D layout col=lane&15, row=quad*4+reg  [m89-verified]
#pragma unroll
  for (int mt = 0; mt < 4; ++mt) {
#pragma unroll
    for (int nt = 0; nt < 4; ++nt) {
      const long mb = m0 + wm * 64 + mt * 16 + quad * 4;
      const int j = n0 + wn * 64 + nt * 16 + l16;
      const float bj = bias[j];
#pragma unroll
      for (int r = 0; r < 4; ++r) {
        const long m = mb + r;
        const float v = acc[mt][nt][r] + bj;
        if constexpr (EPI == EPI_QKV) {
          const int w = (int)(m >> 6), t = (int)(m & 63);
          const int region = j >> 8, hh = (j >> 5) & 7, d = j & 31;
          const long hb = (long)w * 8 + hh;
          if (region == 0)      oQ[(hb * 64 + t) * 32 + d] = __float2bfloat16(v);
          else if (region == 1) oK[(hb * 64 + t) * 32 + d] = __float2bfloat16(v);
          else                  oV[(hb * 32 + d) * 64 + t] = __float2bfloat16(v);  // V^T
        } else if constexpr (EPI == EPI_OUTPROJ) {
          const int w = (int)(m >> 6), t = (int)(m & 63);
          const int b = w >> 8, wi = w & 255;
          const int row = (wi >> 4) * 8 + (t >> 3);
          const int col = (wi & 15) * 8 + (t & 7);
          const long addr = ((long)b * 16384 + row * 128 + col) * 256 + j;
          of32[addr] = v + resid[addr];
        } else if constexpr (EPI == EPI_GELU) {
          const float g = 0.5f * v * (1.0f + erff(v * 0.70710678118654752f));
          obf[m * (long)ldo + j] = __float2bfloat16(g);
        } else {  // EPI_RESID: accumulate into d_out
          const long addr = m * 256 + j;
          of32[addr] += v;
        }
      }
    }
  }
}

// ---------------- fused window attention ------------------------------------
// 1 block / window (64 tokens); wave wv handles heads 2wv, 2wv+1.
__global__ __launch_bounds__(256) void attn_kern(
    const bf16* __restrict__ Qb, const bf16* __restrict__ Kb,
    const bf16* __restrict__ Vtb, bf16* __restrict__ O) {
  __shared__ __align__(16) unsigned short P[4][64 * 72];
  const int lane = threadIdx.x & 63;
  const int wv = threadIdx.x >> 6;
  const int quad = lane >> 4, l16 = lane & 15;
  const long w = blockIdx.x;
  unsigned short* Pw = &P[wv][0];
  const float SC = 0.17677669529663689f;  // 1/sqrt(32)
  const f32x4 fz = {0.f, 0.f, 0.f, 0.f};

#pragma unroll 1
  for (int hi = 0; hi < 2; ++hi) {
    const int h = wv * 2 + hi;
    const bf16* qp = Qb + ((w * 8 + h) * 64) * 32;
    const bf16* kp = Kb + ((w * 8 + h) * 64) * 32;
    const bf16* vt = Vtb + ((w * 8 + h) * 32) * 64;

    bf16x8 qf[4], kf[4];
#pragma unroll
    for (int mt = 0; mt < 4; ++mt)
      qf[mt] = *(const bf16x8*)(qp + (mt * 16 + l16) * 32 + quad * 8);
#pragma unroll
    for (int nt = 0; nt < 4; ++nt)
      kf[nt] = *(const bf16x8*)(kp + (nt * 16 + l16) * 32 + quad * 8);

    f32x4 s[4][4];
#pragma unroll
    for (int a = 0; a < 4; ++a) {
#pragma unroll
      for (int b = 0; b < 4; ++b) s[a][b] = fz;
    }
#pragma unroll
    for (int mt = 0; mt < 4; ++mt) {
#pragma unroll
      for (int nt = 0; nt < 4; ++nt) {
        s[mt][nt] = __builtin_amdgcn_mfma_f32_16x16x32_bf16(qf[mt], kf[nt],
                                                            s[mt][nt], 0, 0, 0);
      }
    }

#pragma unroll
    for (int mt = 0; mt < 4; ++mt) {
#pragma unroll
      for (int r = 0; r < 4; ++r) {
        float a0 = s[mt][0][r] * SC, a1 = s[mt][1][r] * SC;
        float a2 = s[mt][2][r] * SC, a3 = s[mt][3][r] * SC;
        float mx = fmaxf(fmaxf(a0, a1), fmaxf(a2, a3));
#pragma unroll
        for (int off = 8; off > 0; off >>= 1) mx = fmaxf(mx, __shfl_xor(mx, off));
        a0 = __expf(a0 - mx); a1 = __expf(a1 - mx);
        a2 = __expf(a2 - mx); a3 = __expf(a3 - mx);
        float sm = a0 + a1 + a2 + a3;
#pragma unroll
        for (int off = 8; off > 0; off >>= 1) sm += __shfl_xor(sm, off);
        const float iv = 1.0f / sm;
        const int rp = (mt * 16 + quad * 4 + r) * 72;
        Pw[rp + l16]      = bfbits(a0 * iv);
        Pw[rp + 16 + l16] = bfbits(a1 * iv);
        Pw[rp + 32 + l16] = bfbits(a2 * iv);
        Pw[rp + 48 + l16] = bfbits(a3 * iv);
      }
    }

    bf16x8 vf[2][2];
#pragma unroll
    for (int kt = 0; kt < 2; ++kt) {
#pragma unroll
      for (int dt = 0; dt < 2; ++dt)
        vf[kt][dt] = *(const bf16x8*)(vt + (dt * 16 + l16) * 64 + kt * 32 + quad * 8);
    }
    f32x4 oa[4][2];
#pragma unroll
    for (int a = 0; a < 4; ++a) { oa[a][0] = fz; oa[a][1] = fz; }
#pragma unroll
    for (int mt = 0; mt < 4; ++mt) {
      const unsigned short* pr = Pw + (mt * 16 + l16) * 72 + quad * 8;
      const bf16x8 p0 = *(const bf16x8*)(pr);
      const bf16x8 p1 = *(const bf16x8*)(pr + 32);
#pragma unroll
      for (int dt = 0; dt < 2; ++dt) {
        oa[mt][dt] = __builtin_amdgcn_mfma_f32_16x16x32_bf16(p0, vf[0][dt], oa[mt][dt], 0, 0, 0);
        oa[mt][dt] = __builtin_amdgcn_mfma_f32_16x16x32_bf16(p1, vf[1][dt], oa[mt][dt], 0, 0, 0);
      }
    }

#pragma unroll
    for (int mt = 0; mt < 4; ++mt) {
#pragma unroll
      for (int dt = 0; dt < 2; ++dt) {
#pragma unroll
        for (int r = 0; r < 4; ++r) {
          O[(w * 64 + mt * 16 + quad * 4 + r) * 256 + h * 32 + dt * 16 + l16] =
              __float2bfloat16(oa[mt][dt][r]);
        }
      }
    }
  }
}

// ---------------- launch -----------------------------------------------------
extern "C" void kernel_launch(void* const* d_in, const int* in_sizes, int n_in,
                              void* d_out, int out_size, void* d_ws, size_t ws_size,
                              hipStream_t stream) {
  const float* x     = (const float*)d_in[0];
  const float* ln1g  = (const float*)d_in[1];
  const float* ln1b  = (const float*)d_in[2];
  const float* in_w  = (const float*)d_in[3];
  const float* in_b  = (const float*)d_in[4];
  const float* out_w = (const float*)d_in[5];
  const float* out_b = (const float*)d_in[6];
  const float* ln2g  = (const float*)d_in[7];
  const float* ln2b  = (const float*)d_in[8];
  const float* w1    = (const float*)d_in[9];
  const float* b1    = (const float*)d_in[10];
  const float* w2    = (const float*)d_in[11];
  const float* b2    = (const float*)d_in[12];
  float* out = (float*)d_out;

  char* ws = (char*)d_ws;
  const size_t MB = 1ull << 20;
  bf16* Wc   = (bf16*)ws;
  bf16* Wqkv = Wc;
  bf16* Wo   = Wc + 196608;
  bf16* W1c  = Wc + 262144;
  bf16* W2c  = Wc + 524288;
  bf16* XW   = (bf16*)(ws + 2 * MB);
  bf16* Qb   = (bf16*)(ws + 66 * MB);
  bf16* Kb   = (bf16*)(ws + 130 * MB);
  bf16* Vtb  = (bf16*)(ws + 194 * MB);
  bf16* H1   = (bf16*)(ws + 66 * MB);
  bf16* Obuf = XW;
  bf16* Hbuf = XW;

  cvt_w<<<3072, 256, 0, stream>>>(in_w, out_w, w1, w2, Wc);
  ln_kern<true><<<MTOK / 4, 256, 0, stream>>>(x, ln1g, ln1b, XW);
  gemm_db<256, EPI_QKV><<<dim3(MTOK / 128, 6), 256, 0, stream>>>(
      XW, Wqkv, in_b, Qb, Kb, Vtb, nullptr, nullptr, nullptr, 0);
  attn_kern<<<2048, 256, 0, stream>>>(Qb, Kb, Vtb, Obuf);
  gemm_db<256, EPI_OUTPROJ><<<dim3(MTOK / 128, 2), 256, 0, stream>>>(
      Obuf, Wo, out_b, nullptr, nullptr, nullptr, x, out, nullptr, 0);
  ln_kern<false><<<MTOK / 4, 256, 0, stream>>>(out, ln2g, ln2b, Hbuf);
  gemm_db<256, EPI_GELU><<<dim3(MTOK / 128, 8), 256, 0, stream>>>(
      Hbuf, W1c, b1, nullptr, nullptr, nullptr, nullptr, nullptr, H1, 1024);
  gemm_db<1024, EPI_RESID><<<dim3(MTOK / 128, 2), 256, 0, stream>>>(
      H1, W2c, b2, nullptr, nullptr, nullptr, nullptr, out, nullptr, 0);
}

// Round 4
// 887.373 us; speedup vs baseline: 1.3955x; 1.0615x over previous
//
#include <hip/hip_runtime.h>
#include <hip/hip_bf16.h>
#include <cstdint>

#define DEVINL __device__ __forceinline__

using bf16 = __hip_bfloat16;
typedef __bf16 bf16x8 __attribute__((ext_vector_type(8)));
typedef float f32x4 __attribute__((ext_vector_type(4)));

static constexpr int MTOK = 131072;  // B*N tokens

DEVINL void async_ld16(const void* g, void* l) {
  __builtin_amdgcn_global_load_lds(
      (__attribute__((address_space(1))) void*)(g),
      (__attribute__((address_space(3))) void*)(l), 16, 0, 0);
}

DEVINL unsigned short bfbits(float v) {
  bf16 h = __float2bfloat16(v);
  return *reinterpret_cast<unsigned short*>(&h);
}

// Swizzle-packed panel layout for [rows x K] bf16 matrices:
// granule(16B) f = row*8 + (chunk ^ (row&7)), panels of 128x64 linear.
// Element offset of (m, k) with KP = K/64 panels:
DEVINL long pkaddr(long m, int k, int KP) {
  const long tile = m >> 7;
  const int row = (int)(m & 127);
  const int panel = k >> 6;
  const int c8 = ((k & 63) >> 3) ^ (row & 7);
  return ((tile * KP + panel) * 1024 + row * 8 + c8) * 8 + (k & 7);
}

// ---------------- weights fp32 -> packed bf16 -------------------------------
__global__ __launch_bounds__(256) void cvt_w(
    const float* __restrict__ w0, const float* __restrict__ w1,
    const float* __restrict__ w2, const float* __restrict__ w3,
    bf16* __restrict__ out) {
  int i = blockIdx.x * 256 + threadIdx.x;
  float v; long base; int n, k, KP;
  if (i < 196608)       { v = w0[i]; base = 0;      n = i / 256;  k = i & 255;  KP = 4; }
  else if (i < 262144)  { int j = i - 196608; v = w1[j]; base = 196608; n = j / 256; k = j & 255; KP = 4; }
  else if (i < 524288)  { int j = i - 262144; v = w2[j]; base = 262144; n = j / 256; k = j & 255; KP = 4; }
  else                  { int j = i - 524288; v = w3[j]; base = 524288; n = j >> 10; k = j & 1023; KP = 16; }
  out[base + pkaddr(n, k, KP)] = __float2bfloat16(v);
}

// ---------------- LayerNorm (+optional window partition), fp32 -> packed ----
// one wave per token (C=256 -> 4 elems/lane, float4 vectorized)
template <bool REMAP>
__global__ __launch_bounds__(256) void ln_kern(
    const float* __restrict__ x, const float* __restrict__ gw,
    const float* __restrict__ bw, bf16* __restrict__ out) {
  const int lane = threadIdx.x & 63;
  const int wv = threadIdx.x >> 6;
  const long tok = (long)blockIdx.x * 4 + wv;
  const float4 v = *(const float4*)(x + tok * 256 + lane * 4);
  float s = v.x + v.y + v.z + v.w;
#pragma unroll
  for (int off = 32; off > 0; off >>= 1) s += __shfl_xor(s, off);
  const float mean = s * (1.0f / 256.0f);
  const float dx = v.x - mean, dy = v.y - mean, dz = v.z - mean, dw = v.w - mean;
  float q = dx * dx + dy * dy + dz * dz + dw * dw;
#pragma unroll
  for (int off = 32; off > 0; off >>= 1) q += __shfl_xor(q, off);
  const float inv = rsqrtf(q * (1.0f / 256.0f) + 1e-5f);
  long m;
  if (REMAP) {
    const int b = (int)(tok >> 14);
    const int n = (int)(tok & 16383);
    const int row = n >> 7, col = n & 127;
    const int w = b * 256 + (row >> 3) * 16 + (col >> 3);
    const int t = (row & 7) * 8 + (col & 7);
    m = (long)w * 64 + t;
  } else {
    m = tok;
  }
  const float4 g = *(const float4*)(gw + lane * 4);
  const float4 bb = *(const float4*)(bw + lane * 4);
  ushort4 o;
  o.x = bfbits(dx * inv * g.x + bb.x);
  o.y = bfbits(dy * inv * g.y + bb.y);
  o.z = bfbits(dz * inv * g.z + bb.z);
  o.w = bfbits(dw * inv * g.w + bb.w);
  // k = lane*4 -> 8B-aligned within a granule
  *(ushort4*)((unsigned short*)out + pkaddr(m, lane * 4, 4)) = o;
}

// ---------------- GEMM: C = A @ B^T (packed A, packed B, +epilogue) ---------
// Double-buffered LDS, raw single-barrier async pipeline. Staging is fully
// contiguous: one 16KB burst per operand per BK=64 iteration.
enum { EPI_QKV = 0, EPI_OUTPROJ = 1, EPI_GELU = 2, EPI_RESID = 3 };

template <int KP, int EPI>
__global__ __launch_bounds__(256) void gemm_db(
    const bf16* __restrict__ A, const bf16* __restrict__ Bw,
    const float* __restrict__ bias,
    bf16* __restrict__ oQ, bf16* __restrict__ oK, bf16* __restrict__ oV,
    const float* __restrict__ resid, float* __restrict__ of32,
    bf16* __restrict__ obf) {
  __shared__ __align__(16) unsigned short As[2][128 * 64];
  __shared__ __align__(16) unsigned short Bs[2][128 * 64];
  const int tid = threadIdx.x;
  const int lane = tid & 63, wv = tid >> 6;
  const int quad = lane >> 4, l16 = lane & 15;
  const int wm = wv >> 1, wn = wv & 1;
  const int ntile = blockIdx.x;          // n fastest -> A-tile L3 reuse
  const long mtile = blockIdx.y;
  const long m0 = mtile * 128;
  const int n0 = ntile * 128;

  auto stage = [&](int i, int buf) {
    const bf16* Apan = A + (mtile * KP + i) * 8192;
    const bf16* Bpan = Bw + ((long)ntile * KP + i) * 8192;
#pragma unroll
    for (int p = 0; p < 4; ++p) {
      const int f = p * 256 + tid;
      async_ld16(Apan + f * 8, (char*)&As[buf][0] + f * 16);
      async_ld16(Bpan + f * 8, (char*)&Bs[buf][0] + f * 16);
    }
  };

  const f32x4 fz = {0.f, 0.f, 0.f, 0.f};
  f32x4 acc[4][4];
#pragma unroll
  for (int a = 0; a < 4; ++a) {
#pragma unroll
    for (int b = 0; b < 4; ++b) acc[a][b] = fz;
  }

  stage(0, 0);
#pragma unroll 1
  for (int i = 0; i < KP; ++i) {
    __builtin_amdgcn_s_waitcnt(0x0F70);  // vmcnt(0) only
    __builtin_amdgcn_sched_barrier(0);
    __builtin_amdgcn_s_barrier();
    __builtin_amdgcn_sched_barrier(0);
    if (i + 1 < KP) stage(i + 1, (i + 1) & 1);
    const unsigned short* Asb = &As[i & 1][0];
    const unsigned short* Bsb = &Bs[i & 1][0];
#pragma unroll
    for (int kk = 0; kk < 2; ++kk) {
      bf16x8 af[4], bfr[4];
#pragma unroll
      for (int mt = 0; mt < 4; ++mt) {
        const int row = wm * 64 + mt * 16 + l16;
        const int c8 = (kk * 4 + quad) ^ (row & 7);
        af[mt] = *(const bf16x8*)(Asb + row * 64 + c8 * 8);
      }
#pragma unroll
      for (int nt = 0; nt < 4; ++nt) {
        const int row = wn * 64 + nt * 16 + l16;
        const int c8 = (kk * 4 + quad) ^ (row & 7);
        bfr[nt] = *(const bf16x8*)(Bsb + row * 64 + c8 * 8);
      }
#pragma unroll
      for (int mt = 0; mt < 4; ++mt) {
#pragma unroll
        for (int nt = 0; nt < 4; ++nt) {
          acc[mt][nt] = __builtin_amdgcn_mfma_f32_16x16x32_bf16(
              af[mt], bfr[nt], acc[mt][nt], 0, 0, 0);
        }
      }
    }
  }

  // epilogue: C/D layout col=lane&15, row=quad*4+reg  [m89-verified]
#pragma unroll
  for (int mt = 0; mt < 4; ++mt) {
#pragma unroll
    for (int nt = 0; nt < 4; ++nt) {
      const long mb = m0 + wm * 64 + mt * 16 + quad * 4;
      const int j = n0 + wn * 64 + nt * 16 + l16;
      const float bj = bias[j];
#pragma unroll
      for (int r = 0; r < 4; ++r) {
        const long m = mb + r;
        const float v = acc[mt][nt][r] + bj;
        if constexpr (EPI == EPI_QKV) {
          const int w = (int)(m >> 6), t = (int)(m & 63);
          const int region = j >> 8, hh = (j >> 5) & 7, d = j & 31;
          const long hb = (long)w * 8 + hh;
          if (region == 0)      oQ[(hb * 64 + t) * 32 + d] = __float2bfloat16(v);
          else if (region == 1) oK[(hb * 64 + t) * 32 + d] = __float2bfloat16(v);
          else                  oV[(hb * 32 + d) * 64 + t] = __float2bfloat16(v);  // V^T
        } else if constexpr (EPI == EPI_OUTPROJ) {
          const int w = (int)(m >> 6), t = (int)(m & 63);
          const int b = w >> 8, wi = w & 255;
          const int row = (wi >> 4) * 8 + (t >> 3);
          const int col = (wi & 15) * 8 + (t & 7);
          const long addr = ((long)b * 16384 + row * 128 + col) * 256 + j;
          of32[addr] = v + resid[addr];
        } else if constexpr (EPI == EPI_GELU) {
          const float g = 0.5f * v * (1.0f + erff(v * 0.70710678118654752f));
          obf[pkaddr(m, j, 16)] = __float2bfloat16(g);  // packed H1, K=1024
        } else {  // EPI_RESID: accumulate into d_out
          const long addr = m * 256 + j;
          of32[addr] += v;
        }
      }
    }
  }
}

// ---------------- fused window attention ------------------------------------
// 1 block / window (64 tokens); wave wv handles heads 2wv, 2wv+1.
__global__ __launch_bounds__(256) void attn_kern(
    const bf16* __restrict__ Qb, const bf16* __restrict__ Kb,
    const bf16* __restrict__ Vtb, bf16* __restrict__ O) {
  __shared__ __align__(16) unsigned short P[4][64 * 72];
  const int lane = threadIdx.x & 63;
  const int wv = threadIdx.x >> 6;
  const int quad = lane >> 4, l16 = lane & 15;
  const long w = blockIdx.x;
  unsigned short* Pw = &P[wv][0];
  const float SC = 0.17677669529663689f;  // 1/sqrt(32)
  const f32x4 fz = {0.f, 0.f, 0.f, 0.f};

#pragma unroll 1
  for (int hi = 0; hi < 2; ++hi) {
    const int h = wv * 2 + hi;
    const bf16* qp = Qb + ((w * 8 + h) * 64) * 32;
    const bf16* kp = Kb + ((w * 8 + h) * 64) * 32;
    const bf16* vt = Vtb + ((w * 8 + h) * 32) * 64;

    bf16x8 qf[4], kf[4];
#pragma unroll
    for (int mt = 0; mt < 4; ++mt)
      qf[mt] = *(const bf16x8*)(qp + (mt * 16 + l16) * 32 + quad * 8);
#pragma unroll
    for (int nt = 0; nt < 4; ++nt)
      kf[nt] = *(const bf16x8*)(kp + (nt * 16 + l16) * 32 + quad * 8);

    f32x4 s[4][4];
#pragma unroll
    for (int a = 0; a < 4; ++a) {
#pragma unroll
      for (int b = 0; b < 4; ++b) s[a][b] = fz;
    }
#pragma unroll
    for (int mt = 0; mt < 4; ++mt) {
#pragma unroll
      for (int nt = 0; nt < 4; ++nt) {
        s[mt][nt] = __builtin_amdgcn_mfma_f32_16x16x32_bf16(qf[mt], kf[nt],
                                                            s[mt][nt], 0, 0, 0);
      }
    }

#pragma unroll
    for (int mt = 0; mt < 4; ++mt) {
#pragma unroll
      for (int r = 0; r < 4; ++r) {
        float a0 = s[mt][0][r] * SC, a1 = s[mt][1][r] * SC;
        float a2 = s[mt][2][r] * SC, a3 = s[mt][3][r] * SC;
        float mx = fmaxf(fmaxf(a0, a1), fmaxf(a2, a3));
#pragma unroll
        for (int off = 8; off > 0; off >>= 1) mx = fmaxf(mx, __shfl_xor(mx, off));
        a0 = __expf(a0 - mx); a1 = __expf(a1 - mx);
        a2 = __expf(a2 - mx); a3 = __expf(a3 - mx);
        float sm = a0 + a1 + a2 + a3;
#pragma unroll
        for (int off = 8; off > 0; off >>= 1) sm += __shfl_xor(sm, off);
        const float iv = 1.0f / sm;
        const int rp = (mt * 16 + quad * 4 + r) * 72;
        Pw[rp + l16]      = bfbits(a0 * iv);
        Pw[rp + 16 + l16] = bfbits(a1 * iv);
        Pw[rp + 32 + l16] = bfbits(a2 * iv);
        Pw[rp + 48 + l16] = bfbits(a3 * iv);
      }
    }

    bf16x8 vf[2][2];
#pragma unroll
    for (int kt = 0; kt < 2; ++kt) {
#pragma unroll
      for (int dt = 0; dt < 2; ++dt)
        vf[kt][dt] = *(const bf16x8*)(vt + (dt * 16 + l16) * 64 + kt * 32 + quad * 8);
    }
    f32x4 oa[4][2];
#pragma unroll
    for (int a = 0; a < 4; ++a) { oa[a][0] = fz; oa[a][1] = fz; }
#pragma unroll
    for (int mt = 0; mt < 4; ++mt) {
      const unsigned short* pr = Pw + (mt * 16 + l16) * 72 + quad * 8;
      const bf16x8 p0 = *(const bf16x8*)(pr);
      const bf16x8 p1 = *(const bf16x8*)(pr + 32);
#pragma unroll
      for (int dt = 0; dt < 2; ++dt) {
        oa[mt][dt] = __builtin_amdgcn_mfma_f32_16x16x32_bf16(p0, vf[0][dt], oa[mt][dt], 0, 0, 0);
        oa[mt][dt] = __builtin_amdgcn_mfma_f32_16x16x32_bf16(p1, vf[1][dt], oa[mt][dt], 0, 0, 0);
      }
    }

    // store O packed (K=256) for the OUTPROJ GEMM
#pragma unroll
    for (int mt = 0; mt < 4; ++mt) {
#pragma unroll
      for (int dt = 0; dt < 2; ++dt) {
#pragma unroll
        for (int r = 0; r < 4; ++r) {
          const long m = w * 64 + mt * 16 + quad * 4 + r;
          const int k = h * 32 + dt * 16 + l16;
          O[pkaddr(m, k, 4)] = __float2bfloat16(oa[mt][dt][r]);
        }
      }
    }
  }
}

// ---------------- launch -----------------------------------------------------
extern "C" void kernel_launch(void* const* d_in, const int* in_sizes, int n_in,
                              void* d_out, int out_size, void* d_ws, size_t ws_size,
                              hipStream_t stream) {
  const float* x     = (const float*)d_in[0];
  const float* ln1g  = (const float*)d_in[1];
  const float* ln1b  = (const float*)d_in[2];
  const float* in_w  = (const float*)d_in[3];
  const float* in_b  = (const float*)d_in[4];
  const float* out_w = (const float*)d_in[5];
  const float* out_b = (const float*)d_in[6];
  const float* ln2g  = (const float*)d_in[7];
  const float* ln2b  = (const float*)d_in[8];
  const float* w1    = (const float*)d_in[9];
  const float* b1    = (const float*)d_in[10];
  const float* w2    = (const float*)d_in[11];
  const float* b2    = (const float*)d_in[12];
  float* out = (float*)d_out;

  char* ws = (char*)d_ws;
  const size_t MB = 1ull << 20;
  bf16* Wc   = (bf16*)ws;
  bf16* Wqkv = Wc;
  bf16* Wo   = Wc + 196608;
  bf16* W1c  = Wc + 262144;
  bf16* W2c  = Wc + 524288;
  bf16* XW   = (bf16*)(ws + 2 * MB);
  bf16* Qb   = (bf16*)(ws + 66 * MB);
  bf16* Kb   = (bf16*)(ws + 130 * MB);
  bf16* Vtb  = (bf16*)(ws + 194 * MB);
  bf16* H1   = (bf16*)(ws + 66 * MB);
  bf16* Obuf = XW;
  bf16* Hbuf = XW;

  cvt_w<<<3072, 256, 0, stream>>>(in_w, out_w, w1, w2, Wc);
  ln_kern<true><<<MTOK / 4, 256, 0, stream>>>(x, ln1g, ln1b, XW);
  gemm_db<4, EPI_QKV><<<dim3(6, MTOK / 128), 256, 0, stream>>>(
      XW, Wqkv, in_b, Qb, Kb, Vtb, nullptr, nullptr, nullptr);
  attn_kern<<<2048, 256, 0, stream>>>(Qb, Kb, Vtb, Obuf);
  gemm_db<4, EPI_OUTPROJ><<<dim3(2, MTOK / 128), 256, 0, stream>>>(
      Obuf, Wo, out_b, nullptr, nullptr, nullptr, x, out, nullptr);
  ln_kern<false><<<MTOK / 4, 256, 0, stream>>>(out, ln2g, ln2b, Hbuf);
  gemm_db<4, EPI_GELU><<<dim3(8, MTOK / 128), 256, 0, stream>>>(
      Hbuf, W1c, b1, nullptr, nullptr, nullptr, nullptr, nullptr, H1);
  gemm_db<16, EPI_RESID><<<dim3(2, MTOK / 128), 256, 0, stream>>>(
      H1, W2c, b2, nullptr, nullptr, nullptr, nullptr, out, nullptr);
}